// Round 1
// baseline (328.410 us; speedup 1.0000x reference)
//
#include <hip/hip_runtime.h>
#include <math.h>

#define NCAPS 2
#define NIN 91392      // 17*21*16*16
#define DIN 8
#define DOUT 16
#define BATCH 16
#define GRID_A 714     // 714 * 16 iters * 8 n/block-iter = 91392
#define ITERS_A 16
#define TPB 256
#define PART_STRIDE 512  // 16 b * 2 j * 16 o per block

// Pass kernel: recompute u_hat[j,n,o] = sum_i x[b,n,i]*W[j,n,i,o] on the fly.
// PASS 0: s0 partial = sum_n u_hat (c=0.5 folded into reduce kernel)
// PASS 1: d = vin . u (diff over j) via 32-lane butterfly, c = sigmoid, s1 partial
// PASS 2: same with vin = v0+v1
template<int PASS>
__global__ __launch_bounds__(TPB) void caps_pass(
    const float* __restrict__ x, const float* __restrict__ W,
    const float* __restrict__ vin, float* __restrict__ part)
{
    const int t = threadIdx.x;
    const int o = t & 15;          // output dim
    const int j = (t >> 4) & 1;    // capsule
    const int g = t >> 5;          // n-subgroup 0..7
    const int bid = blockIdx.x;

    // preload routing vector: vinreg[b] = vin[b][j][o]
    float vinreg[BATCH];
    if (PASS > 0) {
        #pragma unroll
        for (int b = 0; b < BATCH; ++b)
            vinreg[b] = vin[b * 32 + (t & 31)];
    }

    float acc[BATCH];
    #pragma unroll
    for (int b = 0; b < BATCH; ++b) acc[b] = 0.f;

    const float sgn = j ? -1.f : 1.f;

    for (int k = 0; k < ITERS_A; ++k) {
        const int chunk = bid + k * GRID_A;   // grid-stride over n-chunks of 8
        const int n = chunk * 8 + g;

        // W[j][n][i][o], i stride = 16 floats (64B) -> 16-lane coalesced per i
        float Wr[DIN];
        const float* wp = W + ((size_t)(j * NIN + n) * DIN) * DOUT + o;
        #pragma unroll
        for (int i = 0; i < DIN; ++i) Wr[i] = wp[i * DOUT];

        const float* xp = x + (size_t)n * DIN;
        #pragma unroll
        for (int b = 0; b < BATCH; ++b) {
            const float* xb_p = xp + (size_t)b * (NIN * DIN);
            const float4 xa = *(const float4*)(xb_p);
            const float4 xb = *(const float4*)(xb_p + 4);
            float u = xa.x*Wr[0] + xa.y*Wr[1] + xa.z*Wr[2] + xa.w*Wr[3]
                    + xb.x*Wr[4] + xb.y*Wr[5] + xb.z*Wr[6] + xb.w*Wr[7];
            if (PASS == 0) {
                acc[b] += u;
            } else {
                // d = b0 - b1 = sum over 32 lanes of sgn * vin[j,o]*u[j,o]
                float m = vinreg[b] * u * sgn;
                m += __shfl_xor(m, 1);
                m += __shfl_xor(m, 2);
                m += __shfl_xor(m, 4);
                m += __shfl_xor(m, 8);
                m += __shfl_xor(m, 16);
                const float c = 1.f / (1.f + expf(-sgn * m)); // softmax over 2 caps
                acc[b] += c * u;
            }
        }
    }

    // reduce over the 8 n-subgroups: pair within wave, then across 4 waves
    #pragma unroll
    for (int b = 0; b < BATCH; ++b) acc[b] += __shfl_xor(acc[b], 32);

    __shared__ float red[4][32][BATCH];
    const int wave = t >> 6;
    const int lane = t & 63;
    if (lane < 32) {
        #pragma unroll
        for (int b = 0; b < BATCH; ++b) red[wave][lane][b] = acc[b];
    }
    __syncthreads();
    if (t < 32) {
        #pragma unroll
        for (int b = 0; b < BATCH; ++b) {
            float s = red[0][t][b] + red[1][t][b] + red[2][t][b] + red[3][t][b];
            part[(size_t)bid * PART_STRIDE + b * 32 + t] = s;  // [bid][b][j*16+o]
        }
    }
}

// Reduce partials -> s[b,j,o], squash -> v. 32 blocks = one per (b,j).
// PASS 0: scale s by 0.5 (uniform softmax); writes v0
// PASS 1: writes v0+v1 (routing logits are linear in accumulated v)
// PASS 2: writes final v to d_out
template<int PASS>
__global__ __launch_bounds__(256) void caps_reduce(
    const float* __restrict__ part, const float* __restrict__ vprev,
    float* __restrict__ vout)
{
    const int blk = blockIdx.x;   // b*2 + j
    const int b = blk >> 1, j = blk & 1;
    const int t = threadIdx.x;
    const int o = t & 15;
    const int ch = t >> 4;        // 16 chunks over GRID_A rows
    float s = 0.f;
    for (int g = ch; g < GRID_A; g += 16)
        s += part[(size_t)g * PART_STRIDE + b * 32 + j * 16 + o];
    __shared__ float red[256];
    red[t] = s;
    __syncthreads();
    if (t < 16) {
        float sv = 0.f;
        #pragma unroll
        for (int c = 0; c < 16; ++c) sv += red[c * 16 + t];
        if (PASS == 0) sv *= 0.5f;
        // squash: v = s * sn/(1+sn)/sqrt(sn+eps), sn = |s|^2 over o (16 lanes)
        float sq = sv * sv;
        sq += __shfl_xor(sq, 1);
        sq += __shfl_xor(sq, 2);
        sq += __shfl_xor(sq, 4);
        sq += __shfl_xor(sq, 8);
        const float sn = sq;
        float v = sv * sn / ((1.f + sn) * sqrtf(sn + 1e-7f));
        if (PASS == 1) v += vprev[b * 32 + j * 16 + o];
        vout[b * 32 + j * 16 + o] = v;
    }
}

extern "C" void kernel_launch(void* const* d_in, const int* in_sizes, int n_in,
                              void* d_out, int out_size, void* d_ws, size_t ws_size,
                              hipStream_t stream) {
    const float* x = (const float*)d_in[0];
    const float* W = (const float*)d_in[1];
    float* out = (float*)d_out;

    float* part = (float*)d_ws;                                // 714*512 floats
    float* v0   = part + (size_t)GRID_A * PART_STRIDE;         // 512
    float* vsum = v0 + 512;                                    // 512

    caps_pass<0><<<GRID_A, TPB, 0, stream>>>(x, W, nullptr, part);
    caps_reduce<0><<<32, 256, 0, stream>>>(part, nullptr, v0);
    caps_pass<1><<<GRID_A, TPB, 0, stream>>>(x, W, v0, part);
    caps_reduce<1><<<32, 256, 0, stream>>>(part, v0, vsum);
    caps_pass<2><<<GRID_A, TPB, 0, stream>>>(x, W, vsum, part);
    caps_reduce<2><<<32, 256, 0, stream>>>(part, nullptr, out);
}